// Round 16
// baseline (3742.456 us; speedup 1.0000x reference)
//
#include <hip/hip_runtime.h>
#include <hip/hip_bf16.h>

// Problem constants
#define B_    64
#define T_    512
#define I_    256
#define H_    1024
#define KSTEPS 40          // (I_+H_)/32 slices
#define NGRP  8            // batch groups (blockIdx&7 -> round-robin = 1 XCD each)
#define BG    8            // batch rows per group
#define RPG   32           // ranks (WGs) per group
#define NWG   256          // total recurrence WGs

typedef __bf16 bf16x8 __attribute__((ext_vector_type(8)));
typedef float  f32x4  __attribute__((ext_vector_type(4)));

__device__ __forceinline__ unsigned short f2bf(float f) {
  unsigned u = __builtin_bit_cast(unsigned, f);
  u += 0x7FFFu + ((u >> 16) & 1u);       // round-to-nearest-even
  return (unsigned short)(u >> 16);
}
__device__ __forceinline__ float sigm(float x) { return 1.0f / (1.0f + __expf(-x)); }
__device__ __forceinline__ float tanh_fast(float x) {
  float ax = fabsf(x);
  float e  = __expf(-2.0f * ax);
  float t  = (1.0f - e) / (1.0f + e);
  return x < 0.0f ? -t : t;
}

// ---------------- K0: x [B,T,I] f32 -> xb [T,B,I] bf16 ----------------
__global__ void k_pack_x(const float* __restrict__ x, unsigned short* __restrict__ xb) {
  int idx = blockIdx.x * blockDim.x + threadIdx.x;   // B*T*I/8 = 1,048,576
  int ic = idx & 31;
  int t  = (idx >> 5) & 511;
  int b  = idx >> 14;
  const float* src = x + ((size_t)b * T_ + t) * I_ + ic * 8;
  float4 f0 = *(const float4*)src;
  float4 f1 = *(const float4*)(src + 4);
  unsigned short o[8] = {f2bf(f0.x), f2bf(f0.y), f2bf(f0.z), f2bf(f0.w),
                         f2bf(f1.x), f2bf(f1.y), f2bf(f1.z), f2bf(f1.w)};
  *(uint4*)(xb + ((size_t)t * B_ + b) * I_ + ic * 8) = *(uint4*)o;
}

// ---------------- K1a: pack W into per-(rank,gate,half) B-fragment layout ----------------
// rank r owns cols [r*32, r*32+32) of each gate. q2 = gate*2 + half.
// layout: [((r*8+q2)*40 + kk)*64 + lane] (16B frag); col n = lane&15,
// W row = gate*H + r*32 + half*16 + n, k = kk*32 + (lane>>4)*8 + e.
__global__ void k_pack_w(const float* __restrict__ Wih, const float* __restrict__ Whh,
                         const float* __restrict__ bih, const float* __restrict__ bhh,
                         unsigned short* __restrict__ wpack, float* __restrict__ biasp) {
  int f = blockIdx.x * blockDim.x + threadIdx.x;     // 32*8*40*64 = 655,360
  int l  = f & 63;
  int q  = f >> 6;
  int kk = q % KSTEPS;
  int q2 = q / KSTEPS;
  int half = q2 & 1;
  int gt   = (q2 >> 1) & 3;
  int r    = q2 >> 3;
  int n  = l & 15;
  int grow = gt * H_ + r * 32 + half * 16 + n;
  int k0 = kk * 32 + (l >> 4) * 8;
  unsigned short o[8];
#pragma unroll
  for (int e = 0; e < 8; ++e) {
    int k = k0 + e;
    float val = (k < I_) ? Wih[(size_t)grow * I_ + k] : Whh[(size_t)grow * H_ + (k - I_)];
    o[e] = f2bf(val);
  }
  *(uint4*)(wpack + (size_t)f * 8) = *(uint4*)o;
  if (kk == 0 && (l >> 4) == 0)
    biasp[(r * 4 + gt) * 32 + half * 16 + n] = bih[grow] + bhh[grow];
}

// ---------------- K1b: pack W_fc [I,H] -> fragment layout ----------------
__global__ void k_pack_wfc(const float* __restrict__ Wfc, unsigned short* __restrict__ wfcp) {
  int f = blockIdx.x * blockDim.x + threadIdx.x;     // 32768
  int l  = f & 63;
  int nt = (f >> 6) & 15;
  int kk = f >> 10;
  int n  = nt * 16 + (l & 15);
  int k0 = kk * 32 + (l >> 4) * 8;
  unsigned short o[8];
#pragma unroll
  for (int e = 0; e < 8; ++e) o[e] = f2bf(Wfc[(size_t)n * H_ + k0 + e]);
  *(uint4*)(wfcp + (size_t)f * 8) = *(uint4*)o;
}

// ---------------- K1c: h0 -> bf16 hbuf [B][H]; zero flags ----------------
__global__ void k_init_h(const float* __restrict__ h0, unsigned short* __restrict__ hbuf,
                         unsigned int* __restrict__ flags) {
  int idx = blockIdx.x * blockDim.x + threadIdx.x;   // 8192
  const float* s = h0 + (size_t)idx * 8;
  unsigned short o[8];
#pragma unroll
  for (int e = 0; e < 8; ++e) o[e] = f2bf(s[e]);
  *(uint4*)(hbuf + (size_t)idx * 8) = *(uint4*)o;
  if (idx < 1024) flags[idx] = 0;   // 8 groups x 32 ranks x 4 wave-flags
}

// 32 parallel h-fragment loads (one per-lane address, imm offsets), single wait.
#define HLOAD32(P)                                                          \
  asm volatile(                                                             \
    "global_load_dwordx4 %0,  %32, off\n\t"                                 \
    "global_load_dwordx4 %1,  %32, off offset:64\n\t"                       \
    "global_load_dwordx4 %2,  %32, off offset:128\n\t"                      \
    "global_load_dwordx4 %3,  %32, off offset:192\n\t"                      \
    "global_load_dwordx4 %4,  %32, off offset:256\n\t"                      \
    "global_load_dwordx4 %5,  %32, off offset:320\n\t"                      \
    "global_load_dwordx4 %6,  %32, off offset:384\n\t"                      \
    "global_load_dwordx4 %7,  %32, off offset:448\n\t"                      \
    "global_load_dwordx4 %8,  %32, off offset:512\n\t"                      \
    "global_load_dwordx4 %9,  %32, off offset:576\n\t"                      \
    "global_load_dwordx4 %10, %32, off offset:640\n\t"                      \
    "global_load_dwordx4 %11, %32, off offset:704\n\t"                      \
    "global_load_dwordx4 %12, %32, off offset:768\n\t"                      \
    "global_load_dwordx4 %13, %32, off offset:832\n\t"                      \
    "global_load_dwordx4 %14, %32, off offset:896\n\t"                      \
    "global_load_dwordx4 %15, %32, off offset:960\n\t"                      \
    "global_load_dwordx4 %16, %32, off offset:1024\n\t"                     \
    "global_load_dwordx4 %17, %32, off offset:1088\n\t"                     \
    "global_load_dwordx4 %18, %32, off offset:1152\n\t"                     \
    "global_load_dwordx4 %19, %32, off offset:1216\n\t"                     \
    "global_load_dwordx4 %20, %32, off offset:1280\n\t"                     \
    "global_load_dwordx4 %21, %32, off offset:1344\n\t"                     \
    "global_load_dwordx4 %22, %32, off offset:1408\n\t"                     \
    "global_load_dwordx4 %23, %32, off offset:1472\n\t"                     \
    "global_load_dwordx4 %24, %32, off offset:1536\n\t"                     \
    "global_load_dwordx4 %25, %32, off offset:1600\n\t"                     \
    "global_load_dwordx4 %26, %32, off offset:1664\n\t"                     \
    "global_load_dwordx4 %27, %32, off offset:1728\n\t"                     \
    "global_load_dwordx4 %28, %32, off offset:1792\n\t"                     \
    "global_load_dwordx4 %29, %32, off offset:1856\n\t"                     \
    "global_load_dwordx4 %30, %32, off offset:1920\n\t"                     \
    "global_load_dwordx4 %31, %32, off offset:1984\n\t"                     \
    "s_waitcnt vmcnt(0)"                                                    \
    : "=&v"(h00), "=&v"(h01), "=&v"(h02), "=&v"(h03), "=&v"(h04),           \
      "=&v"(h05), "=&v"(h06), "=&v"(h07), "=&v"(h08), "=&v"(h09),           \
      "=&v"(h10), "=&v"(h11), "=&v"(h12), "=&v"(h13), "=&v"(h14),           \
      "=&v"(h15), "=&v"(h16), "=&v"(h17), "=&v"(h18), "=&v"(h19),           \
      "=&v"(h20), "=&v"(h21), "=&v"(h22), "=&v"(h23), "=&v"(h24),           \
      "=&v"(h25), "=&v"(h26), "=&v"(h27), "=&v"(h28), "=&v"(h29),           \
      "=&v"(h30), "=&v"(h31)                                                \
    : "v"(P) : "memory")

// one K-slice j: 2 MFMAs (col-halves), B from register-resident W
#define STEP2(HF, J, CA, CB)                                                        \
  CA = __builtin_amdgcn_mfma_f32_16x16x32_bf16(__builtin_bit_cast(bf16x8, HF),      \
                                               wr0[J], CA, 0, 0, 0);                \
  CB = __builtin_amdgcn_mfma_f32_16x16x32_bf16(__builtin_bit_cast(bf16x8, HF),      \
                                               wr1[J], CB, 0, 0, 0);

// ---------------- K2: grouped persistent LSTM recurrence, registers-only h-path ----------------
// 256 WGs x 256 threads (4 waves, 1 WG/CU). g = blockIdx&7 (round-robin =>
// XCD-local heuristic), rank r = blockIdx>>3. Group g owns batch rows
// [g*8,+8); rank r owns h-cols [r*32,+32). Wave v owns GATE v (both 16-col
// halves): W_hh in 256 registers (AGPR), W_ih x-part in LDS (shadow only).
// h A-fragments: direct global->reg HLOAD32 from hs[t-1] (L2/L1-local via
// grouping) -- NO LDS h staging, no barrier B, no bank conflicts.
// pacc double-buffered by t&1 -> ONE barrier per step (poll order guards
// cross-step reuse). Waves poll independently (1 dwordx2 sc1 per lane).
// Coherence (placement-independent): sc1 write-through h stores into hs[t]
// (unique addr/step); consumers plain cached loads; flags agent stores, sc1 polls.
__global__ void __launch_bounds__(256, 1) k_lstm(
    const unsigned short* __restrict__ xb, const unsigned short* __restrict__ wpack,
    const float* __restrict__ biasp, const float* __restrict__ c0,
    const unsigned short* __restrict__ hbuf, unsigned short* __restrict__ hs,
    unsigned int* __restrict__ flags) {
  __shared__ uint4 xlds[4608];             // 72 KB (4096 used: x-part W)
  __shared__ f32x4 pacc[2][4][2][64];      // 16 KB double-buffered partials
  const int tid  = threadIdx.x;
  const int wave = tid >> 6, lane = tid & 63;
  const int g = blockIdx.x & 7, r = blockIdx.x >> 3;

  const uint4* wp4 = (const uint4*)wpack;
  { // x-part W (kk 0..7, all 8 q2-tiles of this rank) into LDS
    for (int i = tid; i < 4096; i += 256) {
      int q2 = i >> 9, kk = (i >> 6) & 7, l = i & 63;
      xlds[i] = wp4[((size_t)(r * 8 + q2) * KSTEPS + kk) * 64 + l];
    }
  }
  // h-part W (kk 8..39) for MY gate, both halves: 256 regs (AGPR)
  bf16x8 wr0[32], wr1[32];
#pragma unroll
  for (int j = 0; j < 32; ++j) {
    wr0[j] = __builtin_bit_cast(bf16x8, wp4[((size_t)(r * 8 + wave * 2) * KSTEPS + 8 + j) * 64 + lane]);
    wr1[j] = __builtin_bit_cast(bf16x8, wp4[((size_t)(r * 8 + wave * 2 + 1) * KSTEPS + 8 + j) * 64 + lane]);
  }

  const int arow = (lane & 15) & 7;        // A-frag batch row (2x dup in M)
  const int aoff = (lane >> 4) * 8;        // A-frag k element offset (q*8)
  // tail: lane handles (row = wave*2 + (lane>>5), col = lane&31)
  const int trow = wave * 2 + (lane >> 5);
  const int tcol = lane & 31;
  const int lp   = (trow >> 2) * 16 + (tcol & 15);
  const int te   = trow & 3;
  const int thf  = tcol >> 4;
  const float bv0 = biasp[(r * 4 + wave) * 32 + (lane & 15)];
  const float bv1 = biasp[(r * 4 + wave) * 32 + 16 + (lane & 15)];
  float creg = c0[(size_t)(g * BG + trow) * H_ + r * 32 + tcol];

  __syncthreads();   // xlds ready

  f32x4 xaccA, xaccB;
  auto computeX = [&](int t) {   // post-flag shadow: x loads + LDS B + 16 MFMA
    xaccA = f32x4{bv0, bv0, bv0, bv0};
    xaccB = f32x4{bv1, bv1, bv1, bv1};
    const unsigned short* xrow = xb + ((size_t)t * B_ + g * BG + arow) * I_ + aoff;
#pragma unroll
    for (int kk = 0; kk < 8; ++kk) {
      bf16x8 a  = *(const bf16x8*)(xrow + kk * 32);
      bf16x8 b0 = __builtin_bit_cast(bf16x8, xlds[wave * 1024 + kk * 64 + lane]);
      bf16x8 b1 = __builtin_bit_cast(bf16x8, xlds[wave * 1024 + 512 + kk * 64 + lane]);
      xaccA = __builtin_amdgcn_mfma_f32_16x16x32_bf16(a, b0, xaccA, 0, 0, 0);
      xaccB = __builtin_amdgcn_mfma_f32_16x16x32_bf16(a, b1, xaccB, 0, 0, 0);
    }
  };
  computeX(0);

  for (int t = 0; t < T_; ++t) {
    // ---- wait: each wave polls its group's 128 wave-flags (dwordx2 sc1) ----
    if (t > 0) {
      const unsigned target = (unsigned)t;
      const unsigned long long* fp = (const unsigned long long*)(flags + g * 128) + lane;
      int guard = 0;
      for (;;) {
        unsigned long long v;
        asm volatile("global_load_dwordx2 %0, %1, off sc1\n\ts_waitcnt vmcnt(0)"
                     : "=&v"(v) : "v"(fp) : "memory");
        if (__all(((unsigned)v >= target) && ((unsigned)(v >> 32) >= target))) break;
        if (++guard > (1 << 20)) break;   // safety: never hard-hang
      }
      asm volatile("" ::: "memory");
    }

    // ---- 32 h fragments direct global->reg (L2/L1-local), one batch ----
    const unsigned short* hrow =
        (t == 0) ? hbuf + (size_t)(g * BG + arow) * H_ + aoff
                 : hs + ((size_t)(t - 1) * B_ + g * BG + arow) * H_ + aoff;
    uint4 h00,h01,h02,h03,h04,h05,h06,h07,h08,h09,h10,h11,h12,h13,h14,h15,
          h16,h17,h18,h19,h20,h21,h22,h23,h24,h25,h26,h27,h28,h29,h30,h31;
    HLOAD32(hrow);

    // ---- 64 MFMAs, 4 independent chains, all operands in registers ----
    f32x4 a0 = xaccA, b0 = xaccB;
    f32x4 a1 = {0.f, 0.f, 0.f, 0.f}, b1 = {0.f, 0.f, 0.f, 0.f};
    STEP2(h00,  0, a0, b0) STEP2(h01,  1, a1, b1)
    STEP2(h02,  2, a0, b0) STEP2(h03,  3, a1, b1)
    STEP2(h04,  4, a0, b0) STEP2(h05,  5, a1, b1)
    STEP2(h06,  6, a0, b0) STEP2(h07,  7, a1, b1)
    STEP2(h08,  8, a0, b0) STEP2(h09,  9, a1, b1)
    STEP2(h10, 10, a0, b0) STEP2(h11, 11, a1, b1)
    STEP2(h12, 12, a0, b0) STEP2(h13, 13, a1, b1)
    STEP2(h14, 14, a0, b0) STEP2(h15, 15, a1, b1)
    STEP2(h16, 16, a0, b0) STEP2(h17, 17, a1, b1)
    STEP2(h18, 18, a0, b0) STEP2(h19, 19, a1, b1)
    STEP2(h20, 20, a0, b0) STEP2(h21, 21, a1, b1)
    STEP2(h22, 22, a0, b0) STEP2(h23, 23, a1, b1)
    STEP2(h24, 24, a0, b0) STEP2(h25, 25, a1, b1)
    STEP2(h26, 26, a0, b0) STEP2(h27, 27, a1, b1)
    STEP2(h28, 28, a0, b0) STEP2(h29, 29, a1, b1)
    STEP2(h30, 30, a0, b0) STEP2(h31, 31, a1, b1)

    pacc[t & 1][wave][0][lane] = a0 + a1;
    pacc[t & 1][wave][1][lane] = b0 + b1;
    __syncthreads();   // C: the ONLY barrier per step

    // ---- tail: 2 rows x 32 cols per wave, gates read cross-wave via pacc ----
    const float* pf = (const float*)&pacc[t & 1][0][0][0];
    float gi = pf[((0 * 2 + thf) * 64 + lp) * 4 + te];
    float gf = pf[((1 * 2 + thf) * 64 + lp) * 4 + te];
    float gg = pf[((2 * 2 + thf) * 64 + lp) * 4 + te];
    float go = pf[((3 * 2 + thf) * 64 + lp) * 4 + te];
    float ig = sigm(gi), fg = sigm(gf), g2 = tanh_fast(gg), og = sigm(go);
    float cn = fg * creg + ig * g2;
    creg = cn;
    unsigned hbp = f2bf(og * tanh_fast(cn));

    // pack 4 cols -> 8B sc1 store; 8 stores per row cover one 64B line
    {
      unsigned vpair = hbp | ((unsigned)__shfl_xor((int)hbp, 1) << 16);
      unsigned long long vquad = (unsigned long long)vpair |
          ((unsigned long long)(unsigned)__shfl_xor((int)vpair, 2) << 32);
      if ((lane & 3) == 0) {
        unsigned long long* dst = (unsigned long long*)
            (hs + ((size_t)t * B_ + g * BG + trow) * H_ + (size_t)r * 32 + tcol);
        __hip_atomic_store(dst, vquad, __ATOMIC_RELAXED, __HIP_MEMORY_SCOPE_AGENT);
      }
    }
    asm volatile("s_waitcnt vmcnt(0)" ::: "memory");   // own stores drained
    if (lane == 0)
      __hip_atomic_store(flags + g * 128 + r * 4 + wave, (unsigned)(t + 1),
                         __ATOMIC_RELAXED, __HIP_MEMORY_SCOPE_AGENT);

    // next step's x-part overlaps the coming poll window
    if (t + 1 < T_) computeX(t + 1);
  }
}

// ---------------- K3: out[t,b,:] = hs[t,b,:] @ W_fc^T + b_fc ----------------
__global__ void k_fc(const unsigned short* __restrict__ hs, const unsigned short* __restrict__ wfcp,
                     const float* __restrict__ bfc, float* __restrict__ out) {
  const int bm = blockIdx.x >> 2, bn = blockIdx.x & 3;
  const int tid = threadIdx.x, wave = tid >> 6, lane = tid & 63;
  const int rr   = bm * 64 + wave * 16 + (lane & 15);
  const int kOff = (lane >> 4) * 8;
  const int nb   = bn * 4;
  f32x4 acc[4];
#pragma unroll
  for (int nt = 0; nt < 4; ++nt) {
    float bvv = bfc[(nb + nt) * 16 + (lane & 15)];
    acc[nt] = {bvv, bvv, bvv, bvv};
  }
  const unsigned short* arow = hs + (size_t)rr * H_ + kOff;
#pragma unroll 2
  for (int kk = 0; kk < 32; ++kk) {
    bf16x8 a = *(const bf16x8*)(arow + kk * 32);
#pragma unroll
    for (int nt = 0; nt < 4; ++nt) {
      bf16x8 b = *(const bf16x8*)(wfcp + ((size_t)(kk * 16 + nb + nt) * 64 + lane) * 8);
      acc[nt] = __builtin_amdgcn_mfma_f32_16x16x32_bf16(a, b, acc[nt], 0, 0, 0);
    }
  }
  const int ro = bm * 64 + wave * 16 + (lane >> 4) * 4;
#pragma unroll
  for (int nt = 0; nt < 4; ++nt)
#pragma unroll
    for (int e = 0; e < 4; ++e)
      out[(size_t)(ro + e) * I_ + (nb + nt) * 16 + (lane & 15)] = acc[nt][e];
}

// ---------------- launcher ----------------
extern "C" void kernel_launch(void* const* d_in, const int* in_sizes, int n_in,
                              void* d_out, int out_size, void* d_ws, size_t ws_size,
                              hipStream_t stream) {
  const float* x   = (const float*)d_in[0];
  const float* h0  = (const float*)d_in[1];
  const float* c0  = (const float*)d_in[2];
  const float* Wih = (const float*)d_in[3];
  const float* Whh = (const float*)d_in[4];
  const float* bih = (const float*)d_in[5];
  const float* bhh = (const float*)d_in[6];
  const float* Wfc = (const float*)d_in[7];
  const float* bfc = (const float*)d_in[8];
  float* out = (float*)d_out;

  char* ws = (char*)d_ws;
  unsigned short* xb    = (unsigned short*)(ws + 0);           // 16,777,216
  unsigned short* hsb   = (unsigned short*)(ws + 16777216);    // 67,108,864
  unsigned short* wpk   = (unsigned short*)(ws + 83886080);    // 10,485,760
  float*          biasp = (float*)        (ws + 94371840);     //     16,384
  unsigned short* wfcp  = (unsigned short*)(ws + 94388224);    //    524,288
  unsigned short* hbuf  = (unsigned short*)(ws + 94912512);    //    131,072
  unsigned int*   flg   = (unsigned int*)  (ws + 95043584);    //      8,192

  k_pack_x  <<<4096, 256, 0, stream>>>(x, xb);
  k_pack_w  <<<2560, 256, 0, stream>>>(Wih, Whh, bih, bhh, wpk, biasp);
  k_pack_wfc<<<128,  256, 0, stream>>>(Wfc, wfcp);
  k_init_h  <<<32,   256, 0, stream>>>(h0, hbuf, flg);
  k_lstm    <<<NWG,  256, 0, stream>>>(xb, wpk, biasp, c0, hbuf, hsb, flg);
  k_fc      <<<2048, 256, 0, stream>>>(hsb, wfcp, bfc, out);
}

// Round 17
// 1601.207 us; speedup vs baseline: 2.3373x; 2.3373x over previous
//
#include <hip/hip_runtime.h>
#include <hip/hip_bf16.h>

// Problem constants
#define B_    64
#define T_    512
#define I_    256
#define H_    1024
#define KSTEPS 40          // (I_+H_)/32 slices
#define NGRP  8            // batch groups (blockIdx&7 -> round-robin = 1 XCD each)
#define BG    8            // batch rows per group
#define RPG   32           // ranks (WGs) per group
#define NWG   256          // total recurrence WGs

typedef __bf16 bf16x8 __attribute__((ext_vector_type(8)));
typedef float  f32x4  __attribute__((ext_vector_type(4)));

__device__ __forceinline__ unsigned short f2bf(float f) {
  unsigned u = __builtin_bit_cast(unsigned, f);
  u += 0x7FFFu + ((u >> 16) & 1u);       // round-to-nearest-even
  return (unsigned short)(u >> 16);
}
__device__ __forceinline__ float sigm(float x) { return 1.0f / (1.0f + __expf(-x)); }
__device__ __forceinline__ float tanh_fast(float x) {
  float ax = fabsf(x);
  float e  = __expf(-2.0f * ax);
  float t  = (1.0f - e) / (1.0f + e);
  return x < 0.0f ? -t : t;
}

// ---------------- K0: x [B,T,I] f32 -> xb [T,B,I] bf16 ----------------
__global__ void k_pack_x(const float* __restrict__ x, unsigned short* __restrict__ xb) {
  int idx = blockIdx.x * blockDim.x + threadIdx.x;   // B*T*I/8 = 1,048,576
  int ic = idx & 31;
  int t  = (idx >> 5) & 511;
  int b  = idx >> 14;
  const float* src = x + ((size_t)b * T_ + t) * I_ + ic * 8;
  float4 f0 = *(const float4*)src;
  float4 f1 = *(const float4*)(src + 4);
  unsigned short o[8] = {f2bf(f0.x), f2bf(f0.y), f2bf(f0.z), f2bf(f0.w),
                         f2bf(f1.x), f2bf(f1.y), f2bf(f1.z), f2bf(f1.w)};
  *(uint4*)(xb + ((size_t)t * B_ + b) * I_ + ic * 8) = *(uint4*)o;
}

// ---------------- K1a: pack W into per-(rank,gate,half) B-fragment layout ----------------
// rank r owns cols [r*32, r*32+32) of each gate. q2 = gate*2 + half.
// layout: [((r*8+q2)*40 + kk)*64 + lane] (16B frag); col n = lane&15,
// W row = gate*H + r*32 + half*16 + n, k = kk*32 + (lane>>4)*8 + e.
__global__ void k_pack_w(const float* __restrict__ Wih, const float* __restrict__ Whh,
                         const float* __restrict__ bih, const float* __restrict__ bhh,
                         unsigned short* __restrict__ wpack, float* __restrict__ biasp) {
  int f = blockIdx.x * blockDim.x + threadIdx.x;     // 32*8*40*64 = 655,360
  int l  = f & 63;
  int q  = f >> 6;
  int kk = q % KSTEPS;
  int q2 = q / KSTEPS;
  int half = q2 & 1;
  int gt   = (q2 >> 1) & 3;
  int r    = q2 >> 3;
  int n  = l & 15;
  int grow = gt * H_ + r * 32 + half * 16 + n;
  int k0 = kk * 32 + (l >> 4) * 8;
  unsigned short o[8];
#pragma unroll
  for (int e = 0; e < 8; ++e) {
    int k = k0 + e;
    float val = (k < I_) ? Wih[(size_t)grow * I_ + k] : Whh[(size_t)grow * H_ + (k - I_)];
    o[e] = f2bf(val);
  }
  *(uint4*)(wpack + (size_t)f * 8) = *(uint4*)o;
  if (kk == 0 && (l >> 4) == 0)
    biasp[(r * 4 + gt) * 32 + half * 16 + n] = bih[grow] + bhh[grow];
}

// ---------------- K1b: pack W_fc [I,H] -> fragment layout ----------------
__global__ void k_pack_wfc(const float* __restrict__ Wfc, unsigned short* __restrict__ wfcp) {
  int f = blockIdx.x * blockDim.x + threadIdx.x;     // 32768
  int l  = f & 63;
  int nt = (f >> 6) & 15;
  int kk = f >> 10;
  int n  = nt * 16 + (l & 15);
  int k0 = kk * 32 + (l >> 4) * 8;
  unsigned short o[8];
#pragma unroll
  for (int e = 0; e < 8; ++e) o[e] = f2bf(Wfc[(size_t)n * H_ + k0 + e]);
  *(uint4*)(wfcp + (size_t)f * 8) = *(uint4*)o;
}

// ---------------- K1c: h0 -> bf16 hbuf [B][H]; zero flags ----------------
__global__ void k_init_h(const float* __restrict__ h0, unsigned short* __restrict__ hbuf,
                         unsigned int* __restrict__ flags) {
  int idx = blockIdx.x * blockDim.x + threadIdx.x;   // 8192
  const float* s = h0 + (size_t)idx * 8;
  unsigned short o[8];
#pragma unroll
  for (int e = 0; e < 8; ++e) o[e] = f2bf(s[e]);
  *(uint4*)(hbuf + (size_t)idx * 8) = *(uint4*)o;
  if (idx < 2048) flags[idx] = 0;   // 8 groups x 32 ranks x 8 wave-flags
}

// ---------------- K2: grouped persistent LSTM recurrence, (gate,K-half) waves ----------------
// 256 WGs x 512 threads, 1 WG/CU (~96 KB LDS). g = blockIdx&7 (round-robin =>
// XCD-local heuristic), rank r = blockIdx>>3. Group g owns batch rows
// [g*8,+8); rank r owns h-cols [r*32,+32). Wave v: gate gt=v>>1, K-half
// kh=v&1 -> W_hh for BOTH 16-col halves of its 16 k-slices in 128 REGISTERS;
// A-fragment reads HALVE vs R15 (16 b128/wave, the dominant cost there).
// x-part: kh selects x slices kh*4..kh*4+3 (W from LDS, shadow only); bias
// folded on kh=0. Tail (row-per-wave) sums each gate across kh=0/1 pacc.
// Coherence (placement-independent): sc1 write-through h stores into hs[t]
// (unique addr/step); consumers plain cached loads; flags agent stores, sc1 polls.
__global__ void __launch_bounds__(512, 2) k_lstm(
    const unsigned short* __restrict__ xb, const unsigned short* __restrict__ wpack,
    const float* __restrict__ biasp, const float* __restrict__ c0,
    const unsigned short* __restrict__ hbuf, unsigned short* __restrict__ hs,
    unsigned int* __restrict__ flags) {
  __shared__ unsigned short hlds[8192];    // 16 KB staged h (8 rows x 2048B, swizzled)
  __shared__ f32x4 pacc[8][2][64];         // 16 KB partials [wave][col-half][lane]
  __shared__ uint4 xlds[4096];             // 64 KB x-part W (8 q2-tiles x 8 kk)
  const int tid  = threadIdx.x;
  const int wave = tid >> 6, lane = tid & 63;
  const int g = blockIdx.x & 7, r = blockIdx.x >> 3;
  const int gt = wave >> 1, kh = wave & 1;

  const uint4* wp4 = (const uint4*)wpack;
  { // x-part W (kk 0..7, all 8 q2-tiles of this rank) into LDS
    for (int i = tid; i < 4096; i += 512) {
      int q2 = i >> 9, kk = (i >> 6) & 7, l = i & 63;
      xlds[i] = wp4[((size_t)(r * 8 + q2) * KSTEPS + kk) * 64 + l];
    }
  }
  // h-part W: MY gate, MY 16 k-slices, BOTH col-halves: 128 regs (AGPR-able)
  bf16x8 wr0[16], wr1[16];
#pragma unroll
  for (int j = 0; j < 16; ++j) {
    wr0[j] = __builtin_bit_cast(bf16x8,
        wp4[((size_t)(r * 8 + gt * 2) * KSTEPS + 8 + kh * 16 + j) * 64 + lane]);
    wr1[j] = __builtin_bit_cast(bf16x8,
        wp4[((size_t)(r * 8 + gt * 2 + 1) * KSTEPS + 8 + kh * 16 + j) * 64 + lane]);
  }

  const int row   = (lane & 15) & 7;       // A-frag batch row (2x dup in M)
  const int qo    = (lane >> 4) * 16;      // A-frag k byte offset within slice
  const int rx    = row << 4;              // hlds XOR swizzle mask (kept from R15)
  const int khoff = kh << 10;              // k-half byte offset within hlds row
  const float bv0 = (kh == 0) ? biasp[(r * 4 + gt) * 32 + (lane & 15)] : 0.f;
  const float bv1 = (kh == 0) ? biasp[(r * 4 + gt) * 32 + 16 + (lane & 15)] : 0.f;
  float creg = 0.f;                        // c-state: row=wave, col=r*32+lane
  if (lane < 32)
    creg = c0[(size_t)(g * BG + wave) * H_ + r * 32 + lane];

  __syncthreads();   // xlds ready

  f32x4 xaccA, xaccB;
  auto computeX = [&](int t) {   // post-flag shadow: x loads + LDS B + 8 MFMA
    xaccA = f32x4{bv0, bv0, bv0, bv0};
    xaccB = f32x4{bv1, bv1, bv1, bv1};
    const unsigned short* xrow =
        xb + ((size_t)t * B_ + g * BG + row) * I_ + kh * 128 + (lane >> 4) * 8;
#pragma unroll
    for (int j = 0; j < 4; ++j) {
      bf16x8 a  = *(const bf16x8*)(xrow + j * 32);
      bf16x8 b0 = __builtin_bit_cast(bf16x8, xlds[(gt * 2) * 512 + (kh * 4 + j) * 64 + lane]);
      bf16x8 b1 = __builtin_bit_cast(bf16x8, xlds[(gt * 2 + 1) * 512 + (kh * 4 + j) * 64 + lane]);
      xaccA = __builtin_amdgcn_mfma_f32_16x16x32_bf16(a, b0, xaccA, 0, 0, 0);
      xaccB = __builtin_amdgcn_mfma_f32_16x16x32_bf16(a, b1, xaccB, 0, 0, 0);
    }
  };
  computeX(0);

  for (int t = 0; t < T_; ++t) {
    // ---- wait: wave0 polls this group's 256 wave-flags (1 dwordx4/lane, sc1) ----
    if (t > 0) {
      if (wave == 0) {
        const uint4* fp = (const uint4*)flags + g * 64 + lane;
        const unsigned target = (unsigned)t;
        int guard = 0;
        for (;;) {
          uint4 v;
          asm volatile("global_load_dwordx4 %0, %1, off sc1\n\ts_waitcnt vmcnt(0)"
                       : "=&v"(v) : "v"(fp) : "memory");
          if (__all(v.x >= target && v.y >= target && v.z >= target && v.w >= target)) break;
          if (++guard > (1 << 20)) break;   // safety: never hard-hang
        }
      }
      __syncthreads();   // A: release all waves; orders poll before h loads
    }

    // ---- stage h_prev row=wave (2 KB) into swizzled hlds ----
    {
      const unsigned short* src =
          (t == 0) ? hbuf + (size_t)(g * BG + wave) * H_ + lane * 8
                   : hs + ((size_t)(t - 1) * B_ + g * BG + wave) * H_ + lane * 8;
      uint4 a0 = *(const uint4*)src;
      uint4 a1 = *(const uint4*)(src + 512);
      char* d0 = (char*)hlds + wave * 2048 + ((lane * 16) ^ (wave << 4));
      *(uint4*)d0 = a0;
      *(uint4*)(d0 + 1024) = a1;
    }
    __syncthreads();   // B: hlds ready

    // ---- 32 MFMAs (W in regs, 16 swizzled A-reads), 4 independent chains ----
    f32x4 c0a = xaccA, c1a = xaccB;
    f32x4 c0b = {0.f, 0.f, 0.f, 0.f}, c1b = {0.f, 0.f, 0.f, 0.f};
    const char* hb = (const char*)hlds + row * 2048;
#pragma unroll
    for (int j = 0; j < 16; j += 2) {
      bf16x8 h0f = *(const bf16x8*)(hb + (((khoff + j * 64) + qo) ^ rx));
      bf16x8 h1f = *(const bf16x8*)(hb + (((khoff + (j + 1) * 64) + qo) ^ rx));
      c0a = __builtin_amdgcn_mfma_f32_16x16x32_bf16(h0f, wr0[j], c0a, 0, 0, 0);
      c1a = __builtin_amdgcn_mfma_f32_16x16x32_bf16(h0f, wr1[j], c1a, 0, 0, 0);
      c0b = __builtin_amdgcn_mfma_f32_16x16x32_bf16(h1f, wr0[j + 1], c0b, 0, 0, 0);
      c1b = __builtin_amdgcn_mfma_f32_16x16x32_bf16(h1f, wr1[j + 1], c1b, 0, 0, 0);
    }
    pacc[wave][0][lane] = c0a + c0b;
    pacc[wave][1][lane] = c1a + c1b;
    __syncthreads();   // C: all partials in LDS

    // ---- tail: wave v = ROW v, col = lane (0..31); gate = kh0 + kh1 ----
    unsigned hbp = 0;
    if (lane < 32) {
      const int c  = lane;
      const int lp = ((wave & 4) << 2) | (c & 15);   // D-frag lane for row=wave
      const int e  = wave & 3;
      const int hf = c >> 4;
      const float* pf = (const float*)pacc;
#define PG(v) pf[(((v) * 2 + hf) * 64 + lp) * 4 + e]
      float gi = PG(0) + PG(1);
      float gf = PG(2) + PG(3);
      float gg = PG(4) + PG(5);
      float go = PG(6) + PG(7);
#undef PG
      float ig = sigm(gi), fg = sigm(gf), g2 = tanh_fast(gg), og = sigm(go);
      float cn = fg * creg + ig * g2;
      creg = cn;
      hbp = f2bf(og * tanh_fast(cn));
    }
    // pack 4 cols/8B; 8 stores cover ONE 64B line (coalesced full-line write)
    {
      unsigned vpair = hbp | ((unsigned)__shfl_xor((int)hbp, 1) << 16);
      unsigned long long vquad = (unsigned long long)vpair |
          ((unsigned long long)(unsigned)__shfl_xor((int)vpair, 2) << 32);
      if (lane < 32 && (lane & 3) == 0) {
        unsigned long long* dst = (unsigned long long*)
            (hs + ((size_t)t * B_ + g * BG + wave) * H_ + (size_t)r * 32 + lane);
        __hip_atomic_store(dst, vquad, __ATOMIC_RELAXED, __HIP_MEMORY_SCOPE_AGENT);
      }
    }
    asm volatile("s_waitcnt vmcnt(0)" ::: "memory");   // own line drained
    if (lane == 0)
      __hip_atomic_store(flags + g * 256 + r * 8 + wave, (unsigned)(t + 1),
                         __ATOMIC_RELAXED, __HIP_MEMORY_SCOPE_AGENT);

    // next step's x-part overlaps the coming poll window
    if (t + 1 < T_) computeX(t + 1);
  }
}

// ---------------- K3: out[t,b,:] = hs[t,b,:] @ W_fc^T + b_fc ----------------
__global__ void k_fc(const unsigned short* __restrict__ hs, const unsigned short* __restrict__ wfcp,
                     const float* __restrict__ bfc, float* __restrict__ out) {
  const int bm = blockIdx.x >> 2, bn = blockIdx.x & 3;
  const int tid = threadIdx.x, wave = tid >> 6, lane = tid & 63;
  const int rr   = bm * 64 + wave * 16 + (lane & 15);
  const int kOff = (lane >> 4) * 8;
  const int nb   = bn * 4;
  f32x4 acc[4];
#pragma unroll
  for (int nt = 0; nt < 4; ++nt) {
    float bvv = bfc[(nb + nt) * 16 + (lane & 15)];
    acc[nt] = {bvv, bvv, bvv, bvv};
  }
  const unsigned short* arow = hs + (size_t)rr * H_ + kOff;
#pragma unroll 2
  for (int kk = 0; kk < 32; ++kk) {
    bf16x8 a = *(const bf16x8*)(arow + kk * 32);
#pragma unroll
    for (int nt = 0; nt < 4; ++nt) {
      bf16x8 b = *(const bf16x8*)(wfcp + ((size_t)(kk * 16 + nb + nt) * 64 + lane) * 8);
      acc[nt] = __builtin_amdgcn_mfma_f32_16x16x32_bf16(a, b, acc[nt], 0, 0, 0);
    }
  }
  const int ro = bm * 64 + wave * 16 + (lane >> 4) * 4;
#pragma unroll
  for (int nt = 0; nt < 4; ++nt)
#pragma unroll
    for (int e = 0; e < 4; ++e)
      out[(size_t)(ro + e) * I_ + (nb + nt) * 16 + (lane & 15)] = acc[nt][e];
}

// ---------------- launcher ----------------
extern "C" void kernel_launch(void* const* d_in, const int* in_sizes, int n_in,
                              void* d_out, int out_size, void* d_ws, size_t ws_size,
                              hipStream_t stream) {
  const float* x   = (const float*)d_in[0];
  const float* h0  = (const float*)d_in[1];
  const float* c0  = (const float*)d_in[2];
  const float* Wih = (const float*)d_in[3];
  const float* Whh = (const float*)d_in[4];
  const float* bih = (const float*)d_in[5];
  const float* bhh = (const float*)d_in[6];
  const float* Wfc = (const float*)d_in[7];
  const float* bfc = (const float*)d_in[8];
  float* out = (float*)d_out;

  char* ws = (char*)d_ws;
  unsigned short* xb    = (unsigned short*)(ws + 0);           // 16,777,216
  unsigned short* hsb   = (unsigned short*)(ws + 16777216);    // 67,108,864
  unsigned short* wpk   = (unsigned short*)(ws + 83886080);    // 10,485,760
  float*          biasp = (float*)        (ws + 94371840);     //     16,384
  unsigned short* wfcp  = (unsigned short*)(ws + 94388224);    //    524,288
  unsigned short* hbuf  = (unsigned short*)(ws + 94912512);    //    131,072
  unsigned int*   flg   = (unsigned int*)  (ws + 95043584);    //      8,192

  k_pack_x  <<<4096, 256, 0, stream>>>(x, xb);
  k_pack_w  <<<2560, 256, 0, stream>>>(Wih, Whh, bih, bhh, wpk, biasp);
  k_pack_wfc<<<128,  256, 0, stream>>>(Wfc, wfcp);
  k_init_h  <<<32,   256, 0, stream>>>(h0, hbuf, flg);
  k_lstm    <<<NWG,  512, 0, stream>>>(xb, wpk, biasp, c0, hbuf, hsb, flg);
  k_fc      <<<2048, 256, 0, stream>>>(hsb, wfcp, bfc, out);
}